// Round 3
// baseline (216.518 us; speedup 1.0000x reference)
//
#include <hip/hip_runtime.h>

// Sigmoid-attention: O = sigmoid(Q K^T / sqrt(64)) V, per (b,h). B*H=64, S=2048, D=64.
// R3: same as R2 (register-direct P->PV via 16x16x16 mfma, QPW=32, 1024 blocks)
// but MFMA builtin dispatch guarded for the host pass.

typedef __bf16 bf16_t;
typedef __attribute__((ext_vector_type(8))) __bf16 bf16x8;
typedef __attribute__((ext_vector_type(4))) __bf16 bf16x4;
typedef __attribute__((ext_vector_type(4))) float  f32x4;
typedef __attribute__((ext_vector_type(4))) short  short4v;

#if defined(__HIP_DEVICE_COMPILE__) && __has_builtin(__builtin_amdgcn_exp2f)
#define FAST_EXP2(x) __builtin_amdgcn_exp2f(x)
#else
#define FAST_EXP2(x) exp2f(x)
#endif
#if defined(__HIP_DEVICE_COMPILE__) && __has_builtin(__builtin_amdgcn_rcpf)
#define FAST_RCP(x) __builtin_amdgcn_rcpf(x)
#else
#define FAST_RCP(x) (1.0f / (x))
#endif

static __device__ __forceinline__ f32x4 pv_mfma(bf16x4 a, bf16x4 b, f32x4 c) {
#if defined(__HIP_DEVICE_COMPILE__)
#if __has_builtin(__builtin_amdgcn_mfma_f32_16x16x16_bf16)
    return __builtin_amdgcn_mfma_f32_16x16x16_bf16(a, b, c, 0, 0, 0);
#elif __has_builtin(__builtin_amdgcn_mfma_f32_16x16x16bf16_1k)
    return __builtin_amdgcn_mfma_f32_16x16x16bf16_1k(
        __builtin_bit_cast(short4v, a), __builtin_bit_cast(short4v, b), c, 0, 0, 0);
#else
    f32x4 d;
    asm("v_mfma_f32_16x16x16_bf16 %0, %1, %2, %3"
        : "=v"(d) : "v"(a), "v"(b), "v"(c));
    return d;
#endif
#else
    (void)a; (void)b;
    return c;   // host pass: never executed
#endif
}

static constexpr int SEQ = 2048;
static constexpr int DH  = 64;
static constexpr int KB  = 32;          // keys per k-iteration
static constexpr int NIT = SEQ / KB;    // 64
static constexpr int QPW = 32;          // q rows per wave
static constexpr int QPB = 128;         // q rows per block (4 waves)

__global__ __launch_bounds__(256, 4)
void sigattn_kernel(const float* __restrict__ Qg, const float* __restrict__ Kg,
                    const float* __restrict__ Vg, float* __restrict__ Og)
{
    // Frag-major LDS, all accesses canonical contiguous b128.
    __shared__ bf16_t Kbuf[2][4 * 64 * 8];   // frags: (ks 2) x (dh 2), 8 bf16/lane
    __shared__ bf16_t Vbuf[2][4 * 64 * 8];   // frags: dt 0..3; per lane 8 bf16 = [ks0 j0..3 | ks1 j0..3]

    const int t    = threadIdx.x;
    const int wave = t >> 6;
    const int lane = t & 63;
    const int c16  = lane & 15;
    const int g4   = lane >> 4;

    const int bh    = blockIdx.x;   // 0..63 ; same-head blocks share XCD (id%8 == bh%8)
    const int qtile = blockIdx.y;   // 0..15

    const size_t hbase = (size_t)bh * SEQ * DH;
    const float* Qp = Qg + hbase;
    const float* Kp = Kg + hbase;
    const float* Vp = Vg + hbase;
    float*       Op = Og + hbase;

    const int qwave = qtile * QPB + wave * QPW;

    // ---- Q fragments (regs, pre-scaled by -log2(e)/sqrt(D)) ----
    // B-frag(Q, qs, dh): lane holds Q[qwave + qs*16 + c16][dh*32 + g4*8 + j]
    const float qscale = -0.125f * 1.44269504088896340736f;
    bf16x8 qf[2][2];
    #pragma unroll
    for (int qs = 0; qs < 2; ++qs) {
        #pragma unroll
        for (int dh = 0; dh < 2; ++dh) {
            const float* p = Qp + (size_t)(qwave + qs * 16 + c16) * DH + dh * 32 + g4 * 8;
            f32x4 a = *(const f32x4*)p;
            f32x4 b = *(const f32x4*)(p + 4);
            bf16x8 f;
            f[0] = (bf16_t)(a.x * qscale); f[1] = (bf16_t)(a.y * qscale);
            f[2] = (bf16_t)(a.z * qscale); f[3] = (bf16_t)(a.w * qscale);
            f[4] = (bf16_t)(b.x * qscale); f[5] = (bf16_t)(b.y * qscale);
            f[6] = (bf16_t)(b.z * qscale); f[7] = (bf16_t)(b.w * qscale);
            qf[qs][dh] = f;
        }
    }

    // ---- staging ----
    // K frag fid = wave = ks*2+dh: lane j -> K[kb + ks*16 + c16][dh*32 + g4*8 + j]
    // V frag fid = wave = dt:      lane j -> [h*4+j] = V[kb + h*16 + g4*4 + j][dt*16 + c16]
    f32x4 kst0, kst1;
    float vst[8];
    auto issue_loads = [&](int kb0) {
        const float* pk = Kp + (size_t)(kb0 + (wave >> 1) * 16 + c16) * DH + (wave & 1) * 32 + g4 * 8;
        kst0 = *(const f32x4*)pk;
        kst1 = *(const f32x4*)(pk + 4);
        const float* pv = Vp + (size_t)(kb0 + g4 * 4) * DH + wave * 16 + c16;
        #pragma unroll
        for (int h = 0; h < 2; ++h)
            #pragma unroll
            for (int j = 0; j < 4; ++j)
                vst[h * 4 + j] = pv[(size_t)(h * 16 + j) * DH];
    };
    auto store_lds = [&](int buf) {
        bf16x8 k8;
        k8[0] = (bf16_t)kst0.x; k8[1] = (bf16_t)kst0.y; k8[2] = (bf16_t)kst0.z; k8[3] = (bf16_t)kst0.w;
        k8[4] = (bf16_t)kst1.x; k8[5] = (bf16_t)kst1.y; k8[6] = (bf16_t)kst1.z; k8[7] = (bf16_t)kst1.w;
        *(bf16x8*)&Kbuf[buf][t * 8] = k8;
        bf16x8 v8;
        #pragma unroll
        for (int j = 0; j < 8; ++j) v8[j] = (bf16_t)vst[j];
        *(bf16x8*)&Vbuf[buf][t * 8] = v8;
    };

    issue_loads(0);
    store_lds(0);

    f32x4 acc[2][4] = {};   // [qs][dt], C-layout: row=q (g4*4+r), col=d (c16)

    for (int it = 0; it < NIT; ++it) {
        const int buf = it & 1;
        __syncthreads();
        if (it + 1 < NIT) issue_loads((it + 1) * KB);

        bf16x8 kf[4], vf[4];
        #pragma unroll
        for (int f = 0; f < 4; ++f) kf[f] = *(const bf16x8*)&Kbuf[buf][(f * 64 + lane) * 8];
        #pragma unroll
        for (int f = 0; f < 4; ++f) vf[f] = *(const bf16x8*)&Vbuf[buf][(f * 64 + lane) * 8];

        #pragma unroll
        for (int qs = 0; qs < 2; ++qs) {
            #pragma unroll
            for (int ks = 0; ks < 2; ++ks) {
                // S^T = K*Q^T: C row = key (ks*16 + g4*4 + r), col = q (qs*16 + c16)
                f32x4 s = {0.f, 0.f, 0.f, 0.f};
                s = __builtin_amdgcn_mfma_f32_16x16x32_bf16(kf[ks * 2 + 0], qf[qs][0], s, 0, 0, 0);
                s = __builtin_amdgcn_mfma_f32_16x16x32_bf16(kf[ks * 2 + 1], qf[qs][1], s, 0, 0, 0);
                // sigmoid -> directly the A-frag of 16x16x16 PV mfma:
                // A[m=c16=q][k=g4*4+j=key within ks-half] = p[j]
                bf16x4 p;
                #pragma unroll
                for (int r = 0; r < 4; ++r)
                    p[r] = (bf16_t)FAST_RCP(1.0f + FAST_EXP2(s[r]));
                #pragma unroll
                for (int dt = 0; dt < 4; ++dt) {
                    bf16x4 vb = ks == 0
                        ? __builtin_shufflevector(vf[dt], vf[dt], 0, 1, 2, 3)
                        : __builtin_shufflevector(vf[dt], vf[dt], 4, 5, 6, 7);
                    acc[qs][dt] = pv_mfma(p, vb, acc[qs][dt]);
                }
            }
        }

        if (it + 1 < NIT) store_lds(buf ^ 1);
    }

    // ---- epilogue: C-layout -> global fp32 ----
    #pragma unroll
    for (int qs = 0; qs < 2; ++qs) {
        const int q0 = qwave + qs * 16 + g4 * 4;
        #pragma unroll
        for (int r = 0; r < 4; ++r) {
            float* po = Op + (size_t)(q0 + r) * DH + c16;
            po[0]  = acc[qs][0][r];
            po[16] = acc[qs][1][r];
            po[32] = acc[qs][2][r];
            po[48] = acc[qs][3][r];
        }
    }
}

extern "C" void kernel_launch(void* const* d_in, const int* in_sizes, int n_in,
                              void* d_out, int out_size, void* d_ws, size_t ws_size,
                              hipStream_t stream)
{
    const float* q = (const float*)d_in[0];
    const float* k = (const float*)d_in[1];
    const float* v = (const float*)d_in[2];
    float* o = (float*)d_out;
    dim3 grid(64, SEQ / QPB);   // (bh, qtile)
    sigattn_kernel<<<grid, dim3(256), 0, stream>>>(q, k, v, o);
}

// Round 5
// 201.991 us; speedup vs baseline: 1.0719x; 1.0719x over previous
//
#include <hip/hip_runtime.h>

// Sigmoid-attention: O = sigmoid(Q K^T / 8) V per (b,h). B*H=64, S=2048, D=64.
// R5: prepass converts K,V -> bf16 frag image in d_ws (V k-permuted so sigmoid
// output feeds 16x16x32 PV mfma straight from regs). Main kernel stages via
// global->VGPR(bf16x8)->ds_write_b128 (known-good m93 pattern; R4's
// global_load_lds produced NaN), double-buffered, one barrier/iter.

typedef __bf16 bf16_t;
typedef __attribute__((ext_vector_type(8))) __bf16 bf16x8;
typedef __attribute__((ext_vector_type(4))) __bf16 bf16x4;
typedef __attribute__((ext_vector_type(4))) float  f32x4;

#if defined(__HIP_DEVICE_COMPILE__) && __has_builtin(__builtin_amdgcn_exp2f)
#define FAST_EXP2(x) __builtin_amdgcn_exp2f(x)
#else
#define FAST_EXP2(x) exp2f(x)
#endif
#if defined(__HIP_DEVICE_COMPILE__) && __has_builtin(__builtin_amdgcn_rcpf)
#define FAST_RCP(x) __builtin_amdgcn_rcpf(x)
#else
#define FAST_RCP(x) (1.0f/(x))
#endif

static constexpr int SEQ = 2048;
static constexpr int DH  = 64;
static constexpr int KB  = 32;           // keys per iter
static constexpr int NIT = SEQ / KB;     // 64
static constexpr int QPW = 32;
static constexpr int QPB = 128;
static constexpr int CHUNK = 4096;       // bf16 per (head,iter) ws chunk (8 KB)

// ---------------- prepass: K,V fp32 -> bf16 frag image -------------------
// ws chunk (per head,iter): [0,2048) K frags f=ks*2+dh:
//   slot (f, lane, j) = K[kb + ks*16 + (lane&15)][dh*32 + (lane>>4)*8 + j]
// [2048,4096) V frags f=dt, k-permuted (kappa) to match P's A-frag k-slots:
//   slot (dt, lane, j) = V[kb + kappa][dt*16 + (lane&15)],
//   kappa(g4,j) = (j>>2)*16 + (lane>>4)*4 + (j&3)
__global__ __launch_bounds__(256)
void sigattn_prepass(const float* __restrict__ Kg, const float* __restrict__ Vg,
                     bf16_t* __restrict__ ws)
{
    const int bh = blockIdx.x, it = blockIdx.y;
    const int t  = threadIdx.x;
    const int kb = it * KB;
    const size_t hbase = (size_t)bh * SEQ * DH;
    bf16_t* wbase = ws + ((size_t)bh * NIT + it) * CHUNK;

    // K: thread t fills slot t (16B), reads 8 contiguous floats
    {
        const int f = t >> 6, lane = t & 63;
        const int ks = f >> 1, dh = f & 1, c16 = lane & 15, g4 = lane >> 4;
        const float* p = Kg + hbase + (size_t)(kb + ks * 16 + c16) * DH + dh * 32 + g4 * 8;
        f32x4 a = *(const f32x4*)p;
        f32x4 b = *(const f32x4*)(p + 4);
        bf16x8 o;
        o[0] = (bf16_t)a.x; o[1] = (bf16_t)a.y; o[2] = (bf16_t)a.z; o[3] = (bf16_t)a.w;
        o[4] = (bf16_t)b.x; o[5] = (bf16_t)b.y; o[6] = (bf16_t)b.z; o[7] = (bf16_t)b.w;
        *(bf16x8*)&wbase[(size_t)t * 8] = o;
    }
    // V: thread (c=t&63, rblk=t>>6) reads rows kb+rblk*8..+7 at col c
    // (each row read is 256B coalesced across the wave), writes two 8B chunks.
    {
        const int c = t & 63, rblk = t >> 6;
        const int dt = c >> 4, c16 = c & 15;
        const float* p = Vg + hbase + (size_t)(kb + rblk * 8) * DH + c;
        float v[8];
        #pragma unroll
        for (int i = 0; i < 8; ++i) v[i] = p[(size_t)i * DH];
        const int j0  = (rblk >> 1) * 4;     // rows>=16 -> j slots 4..7
        const int g4a = (rblk & 1) * 2;
        bf16x4 ca, cb;
        #pragma unroll
        for (int i = 0; i < 4; ++i) { ca[i] = (bf16_t)v[i]; cb[i] = (bf16_t)v[4 + i]; }
        bf16_t* vr = wbase + 2048;
        *(bf16x4*)&vr[(size_t)(dt * 64 + g4a * 16 + c16) * 8 + j0]       = ca;
        *(bf16x4*)&vr[(size_t)(dt * 64 + (g4a + 1) * 16 + c16) * 8 + j0] = cb;
    }
}

// ---------------- main kernel -------------------------------------------
__global__ __launch_bounds__(256, 4)
void sigattn_main(const float* __restrict__ Qg, const bf16_t* __restrict__ ws,
                  float* __restrict__ Og)
{
    __shared__ __align__(16) bf16_t buf[2][CHUNK];   // 8KB x2, double-buffered

    const int t    = threadIdx.x;
    const int wave = t >> 6;
    const int lane = t & 63;
    const int c16  = lane & 15;
    const int g4   = lane >> 4;

    const int bh    = blockIdx.x;
    const int qtile = blockIdx.y;

    const float* Qp = Qg + (size_t)bh * SEQ * DH;
    float*       Op = Og + (size_t)bh * SEQ * DH;
    const bf16_t* wsh = ws + (size_t)bh * NIT * CHUNK;

    const int qwave = qtile * QPB + wave * QPW;

    // Q fragments (pre-scaled by -log2(e)/8): B-frag layout
    const float qscale = -0.125f * 1.44269504088896340736f;
    bf16x8 qf[2][2];
    #pragma unroll
    for (int qs = 0; qs < 2; ++qs) {
        #pragma unroll
        for (int dh = 0; dh < 2; ++dh) {
            const float* p = Qp + (size_t)(qwave + qs * 16 + c16) * DH + dh * 32 + g4 * 8;
            f32x4 a = *(const f32x4*)p;
            f32x4 b = *(const f32x4*)(p + 4);
            bf16x8 f;
            f[0] = (bf16_t)(a.x * qscale); f[1] = (bf16_t)(a.y * qscale);
            f[2] = (bf16_t)(a.z * qscale); f[3] = (bf16_t)(a.w * qscale);
            f[4] = (bf16_t)(b.x * qscale); f[5] = (bf16_t)(b.y * qscale);
            f[6] = (bf16_t)(b.z * qscale); f[7] = (bf16_t)(b.w * qscale);
            qf[qs][dh] = f;
        }
    }

    // staging regs: global(bf16x8) -> ds_write_b128
    bf16x8 rK, rV;
    auto gload = [&](int it) {
        const bf16_t* g = wsh + (size_t)it * CHUNK + t * 8;
        rK = *(const bf16x8*)g;
        rV = *(const bf16x8*)(g + 2048);
    };
    auto lstore = [&](int nb) {
        *(bf16x8*)&buf[nb][t * 8]        = rK;
        *(bf16x8*)&buf[nb][2048 + t * 8] = rV;
    };

    gload(0);
    lstore(0);

    f32x4 acc[2][4] = {};   // [qs][dt], C-layout: row=q(g4*4+r), col=d(c16)

    for (int it = 0; it < NIT; ++it) {
        const int cur = it & 1;
        __syncthreads();                     // buf[cur] published; prev reads done
        if (it + 1 < NIT) gload(it + 1);     // next tile global->regs (in flight)

        bf16x8 kf[4], vf[4];
        #pragma unroll
        for (int f = 0; f < 4; ++f) kf[f] = *(const bf16x8*)&buf[cur][(f * 64 + lane) * 8];
        #pragma unroll
        for (int f = 0; f < 4; ++f) vf[f] = *(const bf16x8*)&buf[cur][2048 + (f * 64 + lane) * 8];

        #pragma unroll
        for (int qs = 0; qs < 2; ++qs) {
            // S^T = K*Q^T: lane holds keys {g4*4+r} (s0) and {16+g4*4+r} (s1), q=c16
            f32x4 s0 = {0.f, 0.f, 0.f, 0.f}, s1 = {0.f, 0.f, 0.f, 0.f};
            s0 = __builtin_amdgcn_mfma_f32_16x16x32_bf16(kf[0], qf[qs][0], s0, 0, 0, 0);
            s0 = __builtin_amdgcn_mfma_f32_16x16x32_bf16(kf[1], qf[qs][1], s0, 0, 0, 0);
            s1 = __builtin_amdgcn_mfma_f32_16x16x32_bf16(kf[2], qf[qs][0], s1, 0, 0, 0);
            s1 = __builtin_amdgcn_mfma_f32_16x16x32_bf16(kf[3], qf[qs][1], s1, 0, 0, 0);
            // sigmoid -> bf16x8 = A-frag of 16x16x32 PV; A k-slot g4*8+j holds key
            // kappa(g4,j), matching the prepass V permutation.
            bf16x8 p8;
            #pragma unroll
            for (int r = 0; r < 4; ++r) p8[r]     = (bf16_t)FAST_RCP(1.0f + FAST_EXP2(s0[r]));
            #pragma unroll
            for (int r = 0; r < 4; ++r) p8[4 + r] = (bf16_t)FAST_RCP(1.0f + FAST_EXP2(s1[r]));
            #pragma unroll
            for (int dt = 0; dt < 4; ++dt)
                acc[qs][dt] = __builtin_amdgcn_mfma_f32_16x16x32_bf16(p8, vf[dt], acc[qs][dt], 0, 0, 0);
        }

        if (it + 1 < NIT) lstore(cur ^ 1);   // publish next tile (visible after next barrier)
    }

    #pragma unroll
    for (int qs = 0; qs < 2; ++qs) {
        const int q0 = qwave + qs * 16 + g4 * 4;
        #pragma unroll
        for (int r = 0; r < 4; ++r) {
            float* po = Op + (size_t)(q0 + r) * DH + c16;
            po[0]  = acc[qs][0][r];
            po[16] = acc[qs][1][r];
            po[32] = acc[qs][2][r];
            po[48] = acc[qs][3][r];
        }
    }
}

// ---------------- fallback (R3-style, no ws) -----------------------------
__global__ __launch_bounds__(256, 4)
void sigattn_fallback(const float* __restrict__ Qg, const float* __restrict__ Kg,
                      const float* __restrict__ Vg, float* __restrict__ Og)
{
    __shared__ bf16_t Kbuf[2][4 * 64 * 8];
    __shared__ bf16_t Vbuf[2][4 * 64 * 8];
    const int t = threadIdx.x, wave = t >> 6, lane = t & 63;
    const int c16 = lane & 15, g4 = lane >> 4;
    const int bh = blockIdx.x, qtile = blockIdx.y;
    const size_t hbase = (size_t)bh * SEQ * DH;
    const float* Qp = Qg + hbase; const float* Kp = Kg + hbase;
    const float* Vp = Vg + hbase; float* Op = Og + hbase;
    const int qwave = qtile * QPB + wave * QPW;
    const float qscale = -0.125f * 1.44269504088896340736f;
    bf16x8 qf[2][2];
    #pragma unroll
    for (int qs = 0; qs < 2; ++qs)
        #pragma unroll
        for (int dh = 0; dh < 2; ++dh) {
            const float* p = Qp + (size_t)(qwave + qs * 16 + c16) * DH + dh * 32 + g4 * 8;
            f32x4 a = *(const f32x4*)p; f32x4 b = *(const f32x4*)(p + 4);
            bf16x8 f;
            f[0]=(bf16_t)(a.x*qscale); f[1]=(bf16_t)(a.y*qscale); f[2]=(bf16_t)(a.z*qscale); f[3]=(bf16_t)(a.w*qscale);
            f[4]=(bf16_t)(b.x*qscale); f[5]=(bf16_t)(b.y*qscale); f[6]=(bf16_t)(b.z*qscale); f[7]=(bf16_t)(b.w*qscale);
            qf[qs][dh] = f;
        }
    f32x4 kst0, kst1; float vst[8];
    auto issue_loads = [&](int kb0) {
        const float* pk = Kp + (size_t)(kb0 + (wave >> 1) * 16 + c16) * DH + (wave & 1) * 32 + g4 * 8;
        kst0 = *(const f32x4*)pk; kst1 = *(const f32x4*)(pk + 4);
        const float* pv = Vp + (size_t)(kb0 + g4 * 4) * DH + wave * 16 + c16;
        #pragma unroll
        for (int h = 0; h < 2; ++h)
            #pragma unroll
            for (int j = 0; j < 4; ++j) vst[h * 4 + j] = pv[(size_t)(h * 16 + j) * DH];
    };
    auto store_lds = [&](int buf) {
        bf16x8 k8;
        k8[0]=(bf16_t)kst0.x; k8[1]=(bf16_t)kst0.y; k8[2]=(bf16_t)kst0.z; k8[3]=(bf16_t)kst0.w;
        k8[4]=(bf16_t)kst1.x; k8[5]=(bf16_t)kst1.y; k8[6]=(bf16_t)kst1.z; k8[7]=(bf16_t)kst1.w;
        *(bf16x8*)&Kbuf[buf][t * 8] = k8;
        bf16x8 v8;
        #pragma unroll
        for (int j = 0; j < 8; ++j) v8[j] = (bf16_t)vst[j];
        *(bf16x8*)&Vbuf[buf][t * 8] = v8;
    };
    issue_loads(0); store_lds(0);
    f32x4 acc[2][4] = {};
    for (int it = 0; it < NIT; ++it) {
        const int buf = it & 1;
        __syncthreads();
        if (it + 1 < NIT) issue_loads((it + 1) * KB);
        bf16x8 kf[4], vf[4];
        #pragma unroll
        for (int f = 0; f < 4; ++f) kf[f] = *(const bf16x8*)&Kbuf[buf][(f * 64 + lane) * 8];
        #pragma unroll
        for (int f = 0; f < 4; ++f) vf[f] = *(const bf16x8*)&Vbuf[buf][(f * 64 + lane) * 8];
        #pragma unroll
        for (int qs = 0; qs < 2; ++qs) {
            f32x4 s0 = {0.f,0.f,0.f,0.f}, s1 = {0.f,0.f,0.f,0.f};
            s0 = __builtin_amdgcn_mfma_f32_16x16x32_bf16(kf[0], qf[qs][0], s0, 0, 0, 0);
            s0 = __builtin_amdgcn_mfma_f32_16x16x32_bf16(kf[1], qf[qs][1], s0, 0, 0, 0);
            s1 = __builtin_amdgcn_mfma_f32_16x16x32_bf16(kf[2], qf[qs][0], s1, 0, 0, 0);
            s1 = __builtin_amdgcn_mfma_f32_16x16x32_bf16(kf[3], qf[qs][1], s1, 0, 0, 0);
            bf16x8 p8;
            #pragma unroll
            for (int r = 0; r < 4; ++r) p8[r]     = (bf16_t)FAST_RCP(1.0f + FAST_EXP2(s0[r]));
            #pragma unroll
            for (int r = 0; r < 4; ++r) p8[4 + r] = (bf16_t)FAST_RCP(1.0f + FAST_EXP2(s1[r]));
            // vst[h*4+j] = V[kb + h*16 + g4*4 + j] -> vf slot j holds key kappa(g4,j):
            // same permutation as p8 -> contraction correct.
            #pragma unroll
            for (int dt = 0; dt < 4; ++dt)
                acc[qs][dt] = __builtin_amdgcn_mfma_f32_16x16x32_bf16(p8, vf[dt], acc[qs][dt], 0, 0, 0);
        }
        if (it + 1 < NIT) store_lds(buf ^ 1);
    }
    #pragma unroll
    for (int qs = 0; qs < 2; ++qs) {
        const int q0 = qwave + qs * 16 + g4 * 4;
        #pragma unroll
        for (int r = 0; r < 4; ++r) {
            float* po = Op + (size_t)(q0 + r) * DH + c16;
            po[0]  = acc[qs][0][r];
            po[16] = acc[qs][1][r];
            po[32] = acc[qs][2][r];
            po[48] = acc[qs][3][r];
        }
    }
}

extern "C" void kernel_launch(void* const* d_in, const int* in_sizes, int n_in,
                              void* d_out, int out_size, void* d_ws, size_t ws_size,
                              hipStream_t stream)
{
    const float* q = (const float*)d_in[0];
    const float* k = (const float*)d_in[1];
    const float* v = (const float*)d_in[2];
    float* o = (float*)d_out;
    const size_t need = 64ull * NIT * CHUNK * sizeof(bf16_t);   // 32 MB
    if (ws_size >= need) {
        sigattn_prepass<<<dim3(64, NIT), dim3(256), 0, stream>>>(k, v, (bf16_t*)d_ws);
        sigattn_main<<<dim3(64, SEQ / QPB), dim3(256), 0, stream>>>(q, (const bf16_t*)d_ws, o);
    } else {
        sigattn_fallback<<<dim3(64, SEQ / QPB), dim3(256), 0, stream>>>(q, k, v, o);
    }
}